// Round 2
// baseline (9689.320 us; speedup 1.0000x reference)
//
#include <hip/hip_runtime.h>

typedef short bf16x8 __attribute__((ext_vector_type(8)));
typedef float f32x4 __attribute__((ext_vector_type(4)));

static constexpr int kT = 512;
static constexpr int kN = 64;
static constexpr int kD = 1024;
static constexpr int kH = 1024;
static constexpr int kG = 4 * kH;  // 4096 gate columns

__device__ __forceinline__ unsigned short f2bf(float f) {
  unsigned u = __builtin_bit_cast(unsigned, f);
  return (unsigned short)((u + 0x7fffu + ((u >> 16) & 1u)) >> 16);  // RNE
}
__device__ __forceinline__ unsigned pack2(float a, float b) {
  return (unsigned)f2bf(a) | ((unsigned)f2bf(b) << 16);
}
__device__ __forceinline__ float sigmoidf_(float v) {
  return 1.0f / (1.0f + __expf(-v));
}

// 256 WGs x 256 threads. WG (dom, ug): batch rows dom*16..+15, hidden units
// ug*16..+15. 4 independent barrier domains (batch rows never mix in the
// recurrence). Weights resident in registers (bf16 frags, K-split across the
// 4 waves). No grid sync: t=0 reads h0 directly; counter is memset by host.
__global__ __launch_bounds__(256, 1)
void lstm_persistent(const float* __restrict__ x, const float* __restrict__ h0,
                     const float* __restrict__ Wx, const float* __restrict__ Wh,
                     const float* __restrict__ bias, float* __restrict__ out,
                     unsigned short* __restrict__ hbuf, unsigned int* __restrict__ cnt) {
  __shared__ unsigned short xs[16 * 1024];  // x tile (swizzled); partials alias front 17KB
  __shared__ unsigned short hs[16 * 1024];  // h tile (swizzled)

  const int tid = threadIdx.x;
  const int bx = blockIdx.x;
  const int dom = bx >> 6;   // 0..3
  const int ug = bx & 63;    // 0..63
  const int wv = tid >> 6;   // wave 0..3 (K-split)
  const int lane = tid & 63;

  // ---- B fragments (held in VGPRs for the whole run):
  // B[k][col]: lane holds col = ug*16 + (lane&15), k = kb + ks*32 + (lane>>4)*8 + e
  const int colc = ug * 16 + (lane & 15);
  const int krow = (lane >> 4) * 8;
  const int kb = wv * 256;  // this wave's K quarter
  bf16x8 wxf[4][8], whf[4][8];  // [gate][k-step] -> 256 VGPRs
#pragma unroll
  for (int ct = 0; ct < 4; ++ct) {
#pragma unroll
    for (int ks = 0; ks < 8; ++ks) {
      bf16x8 vx, vh;
#pragma unroll
      for (int e = 0; e < 8; ++e) {
        const size_t k = (size_t)(kb + ks * 32 + krow + e);
        vx[e] = (short)f2bf(Wx[k * kG + ct * kH + colc]);
        vh[e] = (short)f2bf(Wh[k * kG + ct * kH + colc]);
      }
      wxf[ct][ks] = vx;
      whf[ct][ks] = vh;
    }
  }

  // gate-phase identity: thread owns (n_l, j_l)
  const int n_l = tid >> 4;
  const int j_l = tid & 15;
  const int jg = ug * 16 + j_l;
  const float b_i = bias[jg];
  const float b_f = bias[kH + jg];
  const float b_o = bias[2 * kH + jg];
  const float b_g = bias[3 * kH + jg];
  float c = 0.0f;  // cell state lives in a register for all 512 steps

  // staging identity: thread owns row sr, 16B chunks strided 256B (bank-spread)
  const int sr = tid >> 4;          // 0..15
  const int sc = tid & 15;          // chunk id
  const int ssw = (sr & 7) << 4;    // XOR swizzle
  const int sbase = sr * 2048;      // LDS row byte base

  unsigned int* mycnt = cnt + dom * 32;  // 128B-separated counters

  for (int t = 0; t < kT; ++t) {
    // ---- stage x(t): fp32 -> bf16 -> swizzled LDS (8 x 16B chunks / thread)
    {
      const float4* s4 = (const float4*)(x + ((size_t)(dom * 16 + sr) * kT + t) * kD);
#pragma unroll
      for (int i = 0; i < 8; ++i) {
        const float4 f0 = s4[sc * 2 + i * 32];
        const float4 f1 = s4[sc * 2 + i * 32 + 1];
        uint4 p;
        p.x = pack2(f0.x, f0.y); p.y = pack2(f0.z, f0.w);
        p.z = pack2(f1.x, f1.y); p.w = pack2(f1.z, f1.w);
        *(uint4*)((char*)xs + ((sbase + sc * 16 + i * 256) ^ ssw)) = p;
      }
    }
    // ---- stage h(t): t==0 from h0 (fp32->bf16), else from hbuf (bf16)
    if (t == 0) {
      const float4* s4 = (const float4*)(h0 + (size_t)(dom * 16 + sr) * kH);
#pragma unroll
      for (int i = 0; i < 8; ++i) {
        const float4 f0 = s4[sc * 2 + i * 32];
        const float4 f1 = s4[sc * 2 + i * 32 + 1];
        uint4 p;
        p.x = pack2(f0.x, f0.y); p.y = pack2(f0.z, f0.w);
        p.z = pack2(f1.x, f1.y); p.w = pack2(f1.z, f1.w);
        *(uint4*)((char*)hs + ((sbase + sc * 16 + i * 256) ^ ssw)) = p;
      }
    } else {
      const uint4* s4 = (const uint4*)(hbuf + (size_t)(t & 1) * (kN * kH) +
                                       (size_t)(dom * 16 + sr) * kH);
#pragma unroll
      for (int i = 0; i < 8; ++i) {
        const uint4 v = s4[sc + i * 16];
        *(uint4*)((char*)hs + ((sbase + sc * 16 + i * 256) ^ ssw)) = v;
      }
    }
    __syncthreads();

    // ---- MFMA: acc = x_t @ Wx + h @ Wh over this wave's K quarter
    f32x4 acc[4];
#pragma unroll
    for (int ct = 0; ct < 4; ++ct) acc[ct] = (f32x4){0.f, 0.f, 0.f, 0.f};

    const int arow = lane & 15;
    const int abase = arow * 2048;
    const int asw = (arow & 7) << 4;
#pragma unroll
    for (int ks = 0; ks < 8; ++ks) {
      const int kbyte = (kb + ks * 32 + krow) * 2;
      const int aoff = abase + (kbyte ^ asw);
      const bf16x8 ax = *(const bf16x8*)((const char*)xs + aoff);
      const bf16x8 ah = *(const bf16x8*)((const char*)hs + aoff);
#pragma unroll
      for (int ct = 0; ct < 4; ++ct) {
        acc[ct] = __builtin_amdgcn_mfma_f32_16x16x32_bf16(ax, wxf[ct][ks], acc[ct], 0, 0, 0);
        acc[ct] = __builtin_amdgcn_mfma_f32_16x16x32_bf16(ah, whf[ct][ks], acc[ct], 0, 0, 0);
      }
    }
    __syncthreads();  // A-tile reads done before aliasing xs as the partial buffer

    // ---- cross-wave K reduction via LDS partials (pitch 17 to spread banks)
    float* part = (float*)xs;  // 16 tiles x 16 x 17 f32 = 17408B, aliases x tile
#pragma unroll
    for (int ct = 0; ct < 4; ++ct) {
#pragma unroll
      for (int r = 0; r < 4; ++r) {
        const int prow = (lane >> 4) * 4 + r;  // C/D: row=(l>>4)*4+r, col=l&15
        part[(ct * 4 + wv) * 272 + prow * 17 + (lane & 15)] = acc[ct][r];
      }
    }
    __syncthreads();

    // ---- gates
    float a4[4];
#pragma unroll
    for (int g = 0; g < 4; ++g) {
      a4[g] = part[(g * 4 + 0) * 272 + n_l * 17 + j_l]
            + part[(g * 4 + 1) * 272 + n_l * 17 + j_l]
            + part[(g * 4 + 2) * 272 + n_l * 17 + j_l]
            + part[(g * 4 + 3) * 272 + n_l * 17 + j_l];
    }
    const float gi = sigmoidf_(a4[0] + b_i);
    const float gf = sigmoidf_(a4[1] + b_f);
    const float go = sigmoidf_(a4[2] + b_o);
    const float gg = tanhf(a4[3] + b_g);
    c = gf * c + gi * gg;
    const float hv = go * tanhf(c);
    out[((size_t)(dom * 16 + n_l) * kT + t) * kH + jg] = hv;
    hbuf[(size_t)((t + 1) & 1) * (kN * kH) + (size_t)(dom * 16 + n_l) * kH + jg] = f2bf(hv);

    // ---- domain barrier (64 WGs share this batch slice); skip after last step
    if (t < kT - 1) {
      __syncthreads();  // drains vmcnt: all global h stores issued/complete
      if (tid == 0) {
        __threadfence();  // release: L2 writeback to coherence point (cross-XCD)
        atomicAdd(mycnt, 1u);
        const unsigned target = 64u * (unsigned)(t + 1);  // monotonic
        while (__hip_atomic_load(mycnt, __ATOMIC_RELAXED, __HIP_MEMORY_SCOPE_AGENT) < target) {
          __builtin_amdgcn_s_sleep(1);
        }
        __threadfence();  // acquire: invalidate stale L1/L2 before h reads
      }
      __syncthreads();
    }
  }
}

extern "C" void kernel_launch(void* const* d_in, const int* in_sizes, int n_in,
                              void* d_out, int out_size, void* d_ws, size_t ws_size,
                              hipStream_t stream) {
  (void)in_sizes; (void)n_in; (void)out_size; (void)ws_size;
  const float* x  = (const float*)d_in[0];
  const float* h0 = (const float*)d_in[1];
  const float* Wx = (const float*)d_in[2];
  const float* Wh = (const float*)d_in[3];
  const float* b  = (const float*)d_in[4];
  float* out = (float*)d_out;

  // ws layout: [0,4096) barrier counters, [4096, 4096+256KB) h double buffer
  unsigned int* cnt = (unsigned int*)d_ws;
  unsigned short* hbuf = (unsigned short*)((char*)d_ws + 4096);

  hipMemsetAsync(d_ws, 0, 4096, stream);  // reset counters (graph-capture legal)

  void* args[] = { &x, &h0, &Wx, &Wh, &b, &out, &hbuf, &cnt };
  hipError_t e = hipLaunchCooperativeKernel((const void*)lstm_persistent,
                                            dim3(256), dim3(256), args, 0, stream);
  if (e != hipSuccess) {
    (void)hipGetLastError();  // clear sticky error, fall back to plain launch:
    // co-residency guaranteed: >256 VGPR/thread -> 1 block/CU -> 256 blocks on 256 CUs
    hipLaunchKernelGGL(lstm_persistent, dim3(256), dim3(256), 0, stream,
                       x, h0, Wx, Wh, b, out, hbuf, cnt);
  }
}

// Round 3
// 3689.554 us; speedup vs baseline: 2.6261x; 2.6261x over previous
//
#include <hip/hip_runtime.h>

typedef short bf16x8 __attribute__((ext_vector_type(8)));
typedef float f32x4 __attribute__((ext_vector_type(4)));

static constexpr int kT = 512;
static constexpr int kN = 64;
static constexpr int kD = 1024;
static constexpr int kH = 1024;
static constexpr int kG = 4 * kH;  // 4096 gate columns

__device__ __forceinline__ unsigned short f2bf(float f) {
  unsigned u = __builtin_bit_cast(unsigned, f);
  return (unsigned short)((u + 0x7fffu + ((u >> 16) & 1u)) >> 16);  // RNE
}
__device__ __forceinline__ unsigned pack2(float a, float b) {
  return (unsigned)f2bf(a) | ((unsigned)f2bf(b) << 16);
}
__device__ __forceinline__ float sigmoidf_(float v) {
  return 1.0f / (1.0f + __expf(-v));
}

// pre-pass: x fp32 -> bf16 (only when ws_size allows)
__global__ __launch_bounds__(256) void xconv(const float* __restrict__ x,
                                             unsigned short* __restrict__ xbf) {
  const int gid = blockIdx.x * 256 + threadIdx.x;
  const float4* x4 = (const float4*)x;
  uint4* o = (uint4*)xbf;
  for (int i = gid; i < (kN * kT * kD) / 8; i += 2048 * 256) {
    const float4 f0 = x4[2 * i];
    const float4 f1 = x4[2 * i + 1];
    uint4 p;
    p.x = pack2(f0.x, f0.y); p.y = pack2(f0.z, f0.w);
    p.z = pack2(f1.x, f1.y); p.w = pack2(f1.z, f1.w);
    o[i] = p;
  }
}

// 256 WGs x 256 threads, 1 WG/CU. WG (dom, ug): batch rows dom*16..+15,
// hidden cols ug*16..+15. 4 barrier domains; dom=(bx&7)>>1 pairs each domain
// with 2 XCDs (perf-only heuristic, correctness never depends on it).
// NO fences: all cross-WG data uses agent-scope relaxed atomics (sc1 path,
// bypasses L1/L2) so L2 keeps x/weights hot. h-store visibility before the
// arrival add is guaranteed by __syncthreads' vmcnt(0) drain.
template <bool PRE>
__global__ __launch_bounds__(256, 1)
void lstm_persistent(const float* __restrict__ x, const float* __restrict__ h0,
                     const float* __restrict__ Wx, const float* __restrict__ Wh,
                     const float* __restrict__ bias, float* __restrict__ out,
                     unsigned short* __restrict__ hbuf, unsigned int* __restrict__ cnt,
                     const unsigned short* __restrict__ xbf) {
  __shared__ __align__(16) unsigned short xs[16 * 1024];  // x(t) tile, swizzled
  __shared__ __align__(16) unsigned short hs[16 * 1024];  // h(t) tile, swizzled
  __shared__ float ps[16 * 272];                          // partials, pitch 17

  const int tid = threadIdx.x;
  const int bx = blockIdx.x;
  const int dom = (bx & 7) >> 1;                 // 0..3 (XCD pair)
  const int ug = ((bx >> 3) << 1) | (bx & 1);    // 0..63
  const int wv = tid >> 6;                       // wave 0..3 (K-split)
  const int lane = tid & 63;

  // ---- weight fragments resident in VGPRs for the whole run
  const int colc = ug * 16 + (lane & 15);
  const int krow = (lane >> 4) * 8;
  const int kb = wv * 256;  // this wave's K quarter
  bf16x8 wxf[4][8], whf[4][8];
#pragma unroll
  for (int ct = 0; ct < 4; ++ct) {
#pragma unroll
    for (int ks = 0; ks < 8; ++ks) {
      bf16x8 vx, vh;
#pragma unroll
      for (int e = 0; e < 8; ++e) {
        const size_t k = (size_t)(kb + ks * 32 + krow + e);
        vx[e] = (short)f2bf(Wx[k * kG + ct * kH + colc]);
        vh[e] = (short)f2bf(Wh[k * kG + ct * kH + colc]);
      }
      wxf[ct][ks] = vx;
      whf[ct][ks] = vh;
    }
  }

  // gate-phase identity
  const int n_l = tid >> 4;
  const int j_l = tid & 15;
  const int jg = ug * 16 + j_l;
  const float b_i = bias[jg];
  const float b_f = bias[kH + jg];
  const float b_o = bias[2 * kH + jg];
  const float b_g = bias[3 * kH + jg];
  float c = 0.0f;

  // staging identity: row sr, chunk sc
  const int sr = tid >> 4;
  const int sc = tid & 15;
  const int ssw = (sr & 7) << 4;
  const int sbase = sr * 2048;

  unsigned int* base_cnt = cnt + dom * 8 * 32;   // 8 x 128B lines per domain
  const int grp = ug & 7;

  // ---- prologue: stage x(0) and h0
  if (PRE) {
    const uint4* xsrc = (const uint4*)(xbf + ((size_t)(dom * 16 + sr) * kT + 0) * kD);
#pragma unroll
    for (int i = 0; i < 8; ++i)
      *(uint4*)((char*)xs + ((sbase + i * 256 + sc * 16) ^ ssw)) = xsrc[i * 16 + sc];
  } else {
    const float4* s4 = (const float4*)(x + ((size_t)(dom * 16 + sr) * kT + 0) * kD);
#pragma unroll
    for (int i = 0; i < 8; ++i) {
      const float4 f0 = s4[sc * 2 + i * 32];
      const float4 f1 = s4[sc * 2 + i * 32 + 1];
      uint4 p;
      p.x = pack2(f0.x, f0.y); p.y = pack2(f0.z, f0.w);
      p.z = pack2(f1.x, f1.y); p.w = pack2(f1.z, f1.w);
      *(uint4*)((char*)xs + ((sbase + i * 256 + sc * 16) ^ ssw)) = p;
    }
  }
  {
    const float4* s4 = (const float4*)(h0 + (size_t)(dom * 16 + sr) * kH);
#pragma unroll
    for (int i = 0; i < 8; ++i) {
      const float4 f0 = s4[sc * 2 + i * 32];
      const float4 f1 = s4[sc * 2 + i * 32 + 1];
      uint4 p;
      p.x = pack2(f0.x, f0.y); p.y = pack2(f0.z, f0.w);
      p.z = pack2(f1.x, f1.y); p.w = pack2(f1.z, f1.w);
      *(uint4*)((char*)hs + ((sbase + i * 256 + sc * 16) ^ ssw)) = p;
    }
  }
  __syncthreads();

  const int arow = lane & 15;
  const int abase = arow * 2048;
  const int asw = (arow & 7) << 4;

  unsigned long long hreg[16];  // next-step h tile in flight (statically indexed)

  for (int t = 0; t < kT; ++t) {
    // ---- [A] x-half MFMAs (overlaps in-flight hreg loads issued last iter)
    f32x4 acc[4];
#pragma unroll
    for (int ct = 0; ct < 4; ++ct) acc[ct] = (f32x4){0.f, 0.f, 0.f, 0.f};
#pragma unroll
    for (int ks = 0; ks < 8; ++ks) {
      const int aoff = abase + (((kb + ks * 32 + krow) * 2) ^ asw);
      const bf16x8 ax = *(const bf16x8*)((const char*)xs + aoff);
#pragma unroll
      for (int ct = 0; ct < 4; ++ct)
        acc[ct] = __builtin_amdgcn_mfma_f32_16x16x32_bf16(ax, wxf[ct][ks], acc[ct], 0, 0, 0);
    }

    // ---- [B] commit in-flight h(t) tile to LDS (t>0; t==0 staged in prologue)
    if (t > 0) {
#pragma unroll
      for (int j = 0; j < 16; ++j)
        *(unsigned long long*)((char*)hs + ((sbase + (j * 16 + sc) * 8) ^ ssw)) = hreg[j];
      __syncthreads();
    }

    // ---- [C] h-half MFMAs
#pragma unroll
    for (int ks = 0; ks < 8; ++ks) {
      const int aoff = abase + (((kb + ks * 32 + krow) * 2) ^ asw);
      const bf16x8 ah = *(const bf16x8*)((const char*)hs + aoff);
#pragma unroll
      for (int ct = 0; ct < 4; ++ct)
        acc[ct] = __builtin_amdgcn_mfma_f32_16x16x32_bf16(ah, whf[ct][ks], acc[ct], 0, 0, 0);
    }

    // ---- [D] cross-wave K reduction + gates
#pragma unroll
    for (int ct = 0; ct < 4; ++ct) {
#pragma unroll
      for (int r = 0; r < 4; ++r) {
        const int prow = (lane >> 4) * 4 + r;  // C/D: row=(l>>4)*4+r, col=l&15
        ps[(ct * 4 + wv) * 272 + prow * 17 + (lane & 15)] = acc[ct][r];
      }
    }
    __syncthreads();

    float a4[4];
#pragma unroll
    for (int g = 0; g < 4; ++g) {
      a4[g] = ps[(g * 4 + 0) * 272 + n_l * 17 + j_l]
            + ps[(g * 4 + 1) * 272 + n_l * 17 + j_l]
            + ps[(g * 4 + 2) * 272 + n_l * 17 + j_l]
            + ps[(g * 4 + 3) * 272 + n_l * 17 + j_l];
    }
    const float gi = sigmoidf_(a4[0] + b_i);
    const float gf = sigmoidf_(a4[1] + b_f);
    const float go = sigmoidf_(a4[2] + b_o);
    const float gg = tanhf(a4[3] + b_g);
    c = gf * c + gi * gg;
    const float hv = go * tanhf(c);
    __builtin_nontemporal_store(hv, &out[((size_t)(dom * 16 + n_l) * kT + t) * kH + jg]);

    // ---- [E] publish h(t+1), arrive, prefetch x(t+2-1), wait, issue h loads
    if (t < kT - 1) {
      // agent-scope (sc1) paired u32 store: bypasses L2, no fence needed
      const unsigned mybf = (unsigned)f2bf(hv);
      const unsigned up = (unsigned)__shfl_xor((int)mybf, 1);
      if ((j_l & 1) == 0) {
        const size_t eidx = (size_t)((t + 1) & 1) * (kN * kH) +
                            (size_t)(dom * 16 + n_l) * kH + (size_t)(ug * 16 + j_l);
        __hip_atomic_store((unsigned*)(hbuf + eidx), mybf | (up << 16),
                           __ATOMIC_RELAXED, __HIP_MEMORY_SCOPE_AGENT);
      }
      __syncthreads();  // vmcnt(0) drain: all h stores globally visible

      if (tid == 0)
        __hip_atomic_fetch_add(base_cnt + grp * 32, 1u,
                               __ATOMIC_RELAXED, __HIP_MEMORY_SCOPE_AGENT);

      // prefetch x(t+1) into xs — hidden under the barrier wait
      if (PRE) {
        const uint4* xsrc = (const uint4*)(xbf + ((size_t)(dom * 16 + sr) * kT + (t + 1)) * kD);
#pragma unroll
        for (int i = 0; i < 8; ++i)
          *(uint4*)((char*)xs + ((sbase + i * 256 + sc * 16) ^ ssw)) = xsrc[i * 16 + sc];
      } else {
        const float4* s4 = (const float4*)(x + ((size_t)(dom * 16 + sr) * kT + (t + 1)) * kD);
#pragma unroll
        for (int i = 0; i < 8; ++i) {
          const float4 f0 = s4[sc * 2 + i * 32];
          const float4 f1 = s4[sc * 2 + i * 32 + 1];
          uint4 p;
          p.x = pack2(f0.x, f0.y); p.y = pack2(f0.z, f0.w);
          p.z = pack2(f1.x, f1.y); p.w = pack2(f1.z, f1.w);
          *(uint4*)((char*)xs + ((sbase + i * 256 + sc * 16) ^ ssw)) = p;
        }
      }

      if (tid == 0) {
        const unsigned target = 64u * (unsigned)(t + 1);
        for (;;) {
          unsigned s = 0;
#pragma unroll
          for (int g = 0; g < 8; ++g)
            s += __hip_atomic_load(base_cnt + g * 32, __ATOMIC_RELAXED,
                                   __HIP_MEMORY_SCOPE_AGENT);
          if (s >= target) break;
          __builtin_amdgcn_s_sleep(1);
        }
      }
      __syncthreads();

      // issue h(t+1) loads (sc1) — consumed next iteration in [B]
      const unsigned long long* hsrc =
          (const unsigned long long*)(hbuf + (size_t)((t + 1) & 1) * (kN * kH) +
                                      (size_t)(dom * 16 + sr) * kH);
#pragma unroll
      for (int j = 0; j < 16; ++j)
        hreg[j] = __hip_atomic_load(hsrc + j * 16 + sc, __ATOMIC_RELAXED,
                                    __HIP_MEMORY_SCOPE_AGENT);
    }
  }
}

extern "C" void kernel_launch(void* const* d_in, const int* in_sizes, int n_in,
                              void* d_out, int out_size, void* d_ws, size_t ws_size,
                              hipStream_t stream) {
  (void)in_sizes; (void)n_in; (void)out_size;
  const float* x  = (const float*)d_in[0];
  const float* h0 = (const float*)d_in[1];
  const float* Wx = (const float*)d_in[2];
  const float* Wh = (const float*)d_in[3];
  const float* b  = (const float*)d_in[4];
  float* out = (float*)d_out;

  // ws: [0,4KB) counters | [4KB, +256KB) h double buffer | [+, +64MB) bf16 x
  unsigned int* cnt = (unsigned int*)d_ws;
  unsigned short* hbuf = (unsigned short*)((char*)d_ws + 4096);
  unsigned short* xbf = (unsigned short*)((char*)d_ws + 4096 + (size_t)2 * kN * kH * 2);
  const size_t need_pre = 4096 + (size_t)2 * kN * kH * 2 + (size_t)kN * kT * kD * 2;

  hipMemsetAsync(d_ws, 0, 4096, stream);  // reset barrier counters (capture-legal)

  if (ws_size >= need_pre) {
    hipLaunchKernelGGL(xconv, dim3(2048), dim3(256), 0, stream, x, xbf);
    hipLaunchKernelGGL(HIP_KERNEL_NAME(lstm_persistent<true>), dim3(256), dim3(256),
                       0, stream, x, h0, Wx, Wh, b, out, hbuf, cnt, xbf);
  } else {
    hipLaunchKernelGGL(HIP_KERNEL_NAME(lstm_persistent<false>), dim3(256), dim3(256),
                       0, stream, x, h0, Wx, Wh, b, out, hbuf, cnt,
                       (const unsigned short*)nullptr);
  }
}

// Round 4
// 2794.090 us; speedup vs baseline: 3.4678x; 1.3205x over previous
//
#include <hip/hip_runtime.h>

typedef short bf16x8 __attribute__((ext_vector_type(8)));
typedef float f32x4 __attribute__((ext_vector_type(4)));

static constexpr int kT = 512;
static constexpr int kN = 64;
static constexpr int kD = 1024;
static constexpr int kH = 1024;
static constexpr int kG = 4 * kH;  // 4096 gate columns

__device__ __forceinline__ unsigned short f2bf(float f) {
  unsigned u = __builtin_bit_cast(unsigned, f);
  return (unsigned short)((u + 0x7fffu + ((u >> 16) & 1u)) >> 16);  // RNE
}
__device__ __forceinline__ unsigned pack2(float a, float b) {
  return (unsigned)f2bf(a) | ((unsigned)f2bf(b) << 16);
}
__device__ __forceinline__ float sigmoidf_(float v) {
  return 1.0f / (1.0f + __expf(-v));
}

// coherent 16B load (bypass L1+L2 -> device coherence point)
__device__ __forceinline__ bf16x8 gld16_coh(unsigned long long a) {
  bf16x8 r;
  asm volatile("global_load_dwordx4 %0, %1, off sc0 sc1" : "=v"(r) : "v"(a) : "memory");
  return r;
}
// plain cached 16B load (issue-only; hardware readiness via later vmcnt/barrier)
__device__ __forceinline__ bf16x8 gld16(unsigned long long a) {
  bf16x8 r;
  asm volatile("global_load_dwordx4 %0, %1, off" : "=v"(r) : "v"(a) : "memory");
  return r;
}

// pre-pass: x fp32 -> bf16
__global__ __launch_bounds__(256) void xconv(const float* __restrict__ x,
                                             unsigned short* __restrict__ xbf) {
  const int gid = blockIdx.x * 256 + threadIdx.x;
  const float4* x4 = (const float4*)x;
  uint4* o = (uint4*)xbf;
  for (int i = gid; i < (kN * kT * kD) / 8; i += 2048 * 256) {
    const float4 f0 = x4[2 * i];
    const float4 f1 = x4[2 * i + 1];
    uint4 p;
    p.x = pack2(f0.x, f0.y); p.y = pack2(f0.z, f0.w);
    p.z = pack2(f1.x, f1.y); p.w = pack2(f1.z, f1.w);
    o[i] = p;
  }
}

// 256 WGs x 256 threads, 1 WG/CU. WG (dom, ug): batch rows dom*16..+15, hidden
// cols ug*16..+15. 4 barrier domains. A-fragments (x and h rows) load straight
// from global into MFMA registers -- no LDS staging. h goes through the device
// coherence point (sc0 sc1 / agent atomics); visibility ordering: sync1 drains
// vmcnt before the WG's arrival add.
template <bool PRE>
__global__ __launch_bounds__(256, 1)
void lstm_persistent(const float* __restrict__ x, const float* __restrict__ h0,
                     const float* __restrict__ Wx, const float* __restrict__ Wh,
                     const float* __restrict__ bias, float* __restrict__ out,
                     unsigned short* __restrict__ hbuf, unsigned int* __restrict__ cnt,
                     const unsigned short* __restrict__ xbf) {
  __shared__ float ps[16 * 272];  // cross-wave partials, pitch 17

  const int tid = threadIdx.x;
  const int bx = blockIdx.x;
  const int dom = (bx & 7) >> 1;                 // 0..3
  const int ug = ((bx >> 3) << 1) | (bx & 1);    // 0..63
  const int wv = tid >> 6;                       // wave 0..3 (K-split)
  const int lane = tid & 63;

  // ---- weight fragments resident in VGPRs for the whole run
  const int colc = ug * 16 + (lane & 15);
  const int krow = (lane >> 4) * 8;
  const int kb = wv * 256;  // this wave's K quarter
  bf16x8 wxf[4][8], whf[4][8];
#pragma unroll
  for (int ct = 0; ct < 4; ++ct) {
#pragma unroll
    for (int ks = 0; ks < 8; ++ks) {
      bf16x8 vx, vh;
#pragma unroll
      for (int e = 0; e < 8; ++e) {
        const size_t k = (size_t)(kb + ks * 32 + krow + e);
        vx[e] = (short)f2bf(Wx[k * kG + ct * kH + colc]);
        vh[e] = (short)f2bf(Wh[k * kG + ct * kH + colc]);
      }
      wxf[ct][ks] = vx;
      whf[ct][ks] = vh;
    }
  }

  // gate-phase identity
  const int n_l = tid >> 4;
  const int j_l = tid & 15;
  const int jg = ug * 16 + j_l;
  const float b_i = bias[jg];
  const float b_f = bias[kH + jg];
  const float b_o = bias[2 * kH + jg];
  const float b_g = bias[3 * kH + jg];
  float c = 0.0f;

  // A-fragment identity: lane reads row nrow, k-cols kb+ks*32+krow .. +8
  const int arow = lane & 15;
  const int nrow = dom * 16 + arow;
  const unsigned long long xbase0 =
      (unsigned long long)nrow * kT * kD * 2 + (unsigned long long)(kb + krow) * 2;
  const unsigned long long hbase0 =
      (unsigned long long)nrow * kH * 2 + (unsigned long long)(kb + krow) * 2;

  unsigned int* base_cnt = cnt + dom * 8 * 32;  // 8 x 128B lines per domain
  const int grp = ug & 7;

  bf16x8 xfrag[8], hfrag[8];

  // ---- prologue: issue x(0) frag loads, then h0 -> hfrag (f32 cvt)
  if (PRE) {
    const unsigned long long xb = (unsigned long long)xbf + xbase0;
#pragma unroll
    for (int ks = 0; ks < 8; ++ks) xfrag[ks] = gld16(xb + (unsigned)(ks * 64));
  } else {
    const float* xr = x + (size_t)nrow * kT * kD + (kb + krow);
#pragma unroll
    for (int ks = 0; ks < 8; ++ks) {
      const float4 f0 = *(const float4*)(xr + ks * 32);
      const float4 f1 = *(const float4*)(xr + ks * 32 + 4);
      bf16x8 v;
      v[0] = (short)f2bf(f0.x); v[1] = (short)f2bf(f0.y);
      v[2] = (short)f2bf(f0.z); v[3] = (short)f2bf(f0.w);
      v[4] = (short)f2bf(f1.x); v[5] = (short)f2bf(f1.y);
      v[6] = (short)f2bf(f1.z); v[7] = (short)f2bf(f1.w);
      xfrag[ks] = v;
    }
  }
  {
    const float* hr = h0 + (size_t)nrow * kH + (kb + krow);
#pragma unroll
    for (int ks = 0; ks < 8; ++ks) {
      const float4 f0 = *(const float4*)(hr + ks * 32);
      const float4 f1 = *(const float4*)(hr + ks * 32 + 4);
      bf16x8 v;
      v[0] = (short)f2bf(f0.x); v[1] = (short)f2bf(f0.y);
      v[2] = (short)f2bf(f0.z); v[3] = (short)f2bf(f0.w);
      v[4] = (short)f2bf(f1.x); v[5] = (short)f2bf(f1.y);
      v[6] = (short)f2bf(f1.z); v[7] = (short)f2bf(f1.w);
      hfrag[ks] = v;
    }
  }

  // acc starts with the x-half of step 0 (hardware-ready: compiler waits above)
  f32x4 acc[4];
#pragma unroll
  for (int ct = 0; ct < 4; ++ct) acc[ct] = (f32x4){0.f, 0.f, 0.f, 0.f};
#pragma unroll
  for (int ks = 0; ks < 8; ++ks)
#pragma unroll
    for (int ct = 0; ct < 4; ++ct)
      acc[ct] = __builtin_amdgcn_mfma_f32_16x16x32_bf16(xfrag[ks], wxf[ct][ks], acc[ct], 0, 0, 0);

  for (int t = 0; t < kT; ++t) {
    // ---- h-half MFMAs: wait for in-flight hfrag (no-op at t=0)
    asm volatile("s_waitcnt vmcnt(0)" ::: "memory");
    __builtin_amdgcn_sched_barrier(0);
#pragma unroll
    for (int ks = 0; ks < 8; ++ks)
#pragma unroll
      for (int ct = 0; ct < 4; ++ct)
        acc[ct] = __builtin_amdgcn_mfma_f32_16x16x32_bf16(hfrag[ks], whf[ct][ks], acc[ct], 0, 0, 0);

    // ---- cross-wave K reduction + gates
#pragma unroll
    for (int ct = 0; ct < 4; ++ct) {
#pragma unroll
      for (int r = 0; r < 4; ++r) {
        const int prow = (lane >> 4) * 4 + r;  // C/D: row=(l>>4)*4+r, col=l&15
        ps[(ct * 4 + wv) * 272 + prow * 17 + (lane & 15)] = acc[ct][r];
      }
    }
    __syncthreads();

    float a4[4];
#pragma unroll
    for (int g = 0; g < 4; ++g) {
      a4[g] = ps[(g * 4 + 0) * 272 + n_l * 17 + j_l]
            + ps[(g * 4 + 1) * 272 + n_l * 17 + j_l]
            + ps[(g * 4 + 2) * 272 + n_l * 17 + j_l]
            + ps[(g * 4 + 3) * 272 + n_l * 17 + j_l];
    }
    const float gi = sigmoidf_(a4[0] + b_i);
    const float gf = sigmoidf_(a4[1] + b_f);
    const float go = sigmoidf_(a4[2] + b_o);
    const float gg = tanhf(a4[3] + b_g);
    c = gf * c + gi * gg;
    const float hv = go * tanhf(c);
    __builtin_nontemporal_store(hv, &out[((size_t)(dom * 16 + n_l) * kT + t) * kH + jg]);

    if (t < kT - 1) {
      // ---- publish h(t+1): paired dword agent-scope store (proven path)
      const unsigned mybf = (unsigned)f2bf(hv);
      const unsigned up = (unsigned)__shfl_xor((int)mybf, 1);
      if ((j_l & 1) == 0) {
        const size_t eidx = (size_t)((t + 1) & 1) * (kN * kH) +
                            (size_t)(dom * 16 + n_l) * kH + (size_t)(ug * 16 + j_l);
        __hip_atomic_store((unsigned*)(hbuf + eidx), mybf | (up << 16),
                           __ATOMIC_RELAXED, __HIP_MEMORY_SCOPE_AGENT);
      }
      __syncthreads();  // sync1: vmcnt(0) drain -> all h stores globally visible

      if (tid == 0)
        __hip_atomic_fetch_add(base_cnt + grp * 32, 1u,
                               __ATOMIC_RELAXED, __HIP_MEMORY_SCOPE_AGENT);

      // ---- x-frag loads + x-half MFMAs for t+1 (hidden under barrier wait)
      if (PRE) {
        const unsigned long long xb = (unsigned long long)xbf + xbase0 +
                                      (unsigned long long)(t + 1) * 2048u;
#pragma unroll
        for (int ks = 0; ks < 8; ++ks) xfrag[ks] = gld16(xb + (unsigned)(ks * 64));
        asm volatile("s_waitcnt vmcnt(0)" ::: "memory");
        __builtin_amdgcn_sched_barrier(0);
      } else {
        const float* xr = x + (size_t)nrow * kT * kD + (size_t)(t + 1) * kD + (kb + krow);
#pragma unroll
        for (int ks = 0; ks < 8; ++ks) {
          const float4 f0 = *(const float4*)(xr + ks * 32);
          const float4 f1 = *(const float4*)(xr + ks * 32 + 4);
          bf16x8 v;
          v[0] = (short)f2bf(f0.x); v[1] = (short)f2bf(f0.y);
          v[2] = (short)f2bf(f0.z); v[3] = (short)f2bf(f0.w);
          v[4] = (short)f2bf(f1.x); v[5] = (short)f2bf(f1.y);
          v[6] = (short)f2bf(f1.z); v[7] = (short)f2bf(f1.w);
          xfrag[ks] = v;
        }
      }
#pragma unroll
      for (int ct = 0; ct < 4; ++ct) acc[ct] = (f32x4){0.f, 0.f, 0.f, 0.f};
#pragma unroll
      for (int ks = 0; ks < 8; ++ks)
#pragma unroll
        for (int ct = 0; ct < 4; ++ct)
          acc[ct] = __builtin_amdgcn_mfma_f32_16x16x32_bf16(xfrag[ks], wxf[ct][ks], acc[ct], 0, 0, 0);

      // ---- per-wave poll (lane 0 of each wave; no broadcast barrier needed)
      if (lane == 0) {
        const unsigned target = 64u * (unsigned)(t + 1);
        for (;;) {
          unsigned s = 0;
#pragma unroll
          for (int g = 0; g < 8; ++g)
            s += __hip_atomic_load(base_cnt + g * 32, __ATOMIC_RELAXED,
                                   __HIP_MEMORY_SCOPE_AGENT);
          if (s >= target) break;
          __builtin_amdgcn_s_sleep(1);
        }
      }
      asm volatile("" ::: "memory");       // pin h-loads after the poll
      __builtin_amdgcn_sched_barrier(0);

      // ---- issue h(t+1) frag loads (coherent), consumed at next iter top
      {
        const unsigned long long hb = (unsigned long long)hbuf +
                                      (unsigned long long)((t + 1) & 1) * (kN * kH * 2) +
                                      hbase0;
#pragma unroll
        for (int ks = 0; ks < 8; ++ks) hfrag[ks] = gld16_coh(hb + (unsigned)(ks * 64));
      }
    }
  }
}

extern "C" void kernel_launch(void* const* d_in, const int* in_sizes, int n_in,
                              void* d_out, int out_size, void* d_ws, size_t ws_size,
                              hipStream_t stream) {
  (void)in_sizes; (void)n_in; (void)out_size;
  const float* x  = (const float*)d_in[0];
  const float* h0 = (const float*)d_in[1];
  const float* Wx = (const float*)d_in[2];
  const float* Wh = (const float*)d_in[3];
  const float* b  = (const float*)d_in[4];
  float* out = (float*)d_out;

  // ws: [0,4KB) counters | [4KB, +256KB) h double buffer | [+, +64MB) bf16 x
  unsigned int* cnt = (unsigned int*)d_ws;
  unsigned short* hbuf = (unsigned short*)((char*)d_ws + 4096);
  unsigned short* xbf = (unsigned short*)((char*)d_ws + 4096 + (size_t)2 * kN * kH * 2);
  const size_t need_pre = 4096 + (size_t)2 * kN * kH * 2 + (size_t)kN * kT * kD * 2;

  hipMemsetAsync(d_ws, 0, 4096, stream);  // reset barrier counters (capture-legal)

  if (ws_size >= need_pre) {
    hipLaunchKernelGGL(xconv, dim3(2048), dim3(256), 0, stream, x, xbf);
    hipLaunchKernelGGL(HIP_KERNEL_NAME(lstm_persistent<true>), dim3(256), dim3(256),
                       0, stream, x, h0, Wx, Wh, b, out, hbuf, cnt, xbf);
  } else {
    hipLaunchKernelGGL(HIP_KERNEL_NAME(lstm_persistent<false>), dim3(256), dim3(256),
                       0, stream, x, h0, Wx, Wh, b, out, hbuf, cnt,
                       (const unsigned short*)nullptr);
  }
}

// Round 5
// 2476.576 us; speedup vs baseline: 3.9124x; 1.1282x over previous
//
#include <hip/hip_runtime.h>

typedef short bf16x8 __attribute__((ext_vector_type(8)));
typedef float f32x4 __attribute__((ext_vector_type(4)));

static constexpr int kT = 512;
static constexpr int kN = 64;
static constexpr int kD = 1024;
static constexpr int kH = 1024;
static constexpr int kG = 4 * kH;  // 4096 gate columns

__device__ __forceinline__ unsigned short f2bf(float f) {
  unsigned u = __builtin_bit_cast(unsigned, f);
  return (unsigned short)((u + 0x7fffu + ((u >> 16) & 1u)) >> 16);  // RNE
}
__device__ __forceinline__ unsigned pack2(float a, float b) {
  return (unsigned)f2bf(a) | ((unsigned)f2bf(b) << 16);
}
// branch-free fast gates: v_exp_f32 + v_rcp_f32 (~1e-7 rel, fine vs 1.8e-2 budget)
__device__ __forceinline__ float fsigmoid(float v) {
  return __builtin_amdgcn_rcpf(1.0f + __expf(-v));
}
__device__ __forceinline__ float ftanh(float v) {
  return 1.0f - 2.0f * __builtin_amdgcn_rcpf(__expf(2.0f * v) + 1.0f);
}

// coherent 16B load (bypass L1+L2 -> device coherence point)
__device__ __forceinline__ bf16x8 gld16_coh(unsigned long long a) {
  bf16x8 r;
  asm volatile("global_load_dwordx4 %0, %1, off sc0 sc1" : "=v"(r) : "v"(a) : "memory");
  return r;
}
// plain cached 16B load (issue-only; readiness via later explicit vmcnt)
__device__ __forceinline__ bf16x8 gld16(unsigned long long a) {
  bf16x8 r;
  asm volatile("global_load_dwordx4 %0, %1, off" : "=v"(r) : "v"(a) : "memory");
  return r;
}

// pre-pass: x fp32 -> bf16
__global__ __launch_bounds__(256) void xconv(const float* __restrict__ x,
                                             unsigned short* __restrict__ xbf) {
  const int gid = blockIdx.x * 256 + threadIdx.x;
  const float4* x4 = (const float4*)x;
  uint4* o = (uint4*)xbf;
  for (int i = gid; i < (kN * kT * kD) / 8; i += 2048 * 256) {
    const float4 f0 = x4[2 * i];
    const float4 f1 = x4[2 * i + 1];
    uint4 p;
    p.x = pack2(f0.x, f0.y); p.y = pack2(f0.z, f0.w);
    p.z = pack2(f1.x, f1.y); p.w = pack2(f1.z, f1.w);
    o[i] = p;
  }
}

// 256 WGs x 256 threads, 1 WG/CU. WG (dom, ug): batch rows dom*16..+15, hidden
// cols ug*16..+15. Per-WAVE arrival (vmcnt is per-wave -> no pre-arrival
// __syncthreads): each wave's lane0 bumps its WG's private counter line after
// draining its own hbuf stores. One aggregator wave per domain (ug==0, wv==0)
// gathers 64 counters with one 64-lane load + butterfly sum, then writes an
// epoch flag; everyone else polls that single read-only line.
template <bool PRE>
__global__ __launch_bounds__(256, 1)
void lstm_persistent(const float* __restrict__ x, const float* __restrict__ h0,
                     const float* __restrict__ Wx, const float* __restrict__ Wh,
                     const float* __restrict__ bias, float* __restrict__ out,
                     unsigned short* __restrict__ hbuf, unsigned int* __restrict__ cnt,
                     const unsigned short* __restrict__ xbf) {
  __shared__ float ps[16 * 320];  // partials: [tile][col(pitch20)][row], b128-writable

  const int tid = threadIdx.x;
  const int bx = blockIdx.x;
  const int dom = (bx & 7) >> 1;                 // 0..3
  const int ug = ((bx >> 3) << 1) | (bx & 1);    // 0..63 (ug==0 <-> bx in {0,2,4,6})
  const int wv = tid >> 6;                       // wave 0..3 (K-split)
  const int lane = tid & 63;

  // ---- weight fragments resident in VGPRs/AGPRs for the whole run
  const int colc = ug * 16 + (lane & 15);
  const int krow = (lane >> 4) * 8;
  const int kb = wv * 256;  // this wave's K quarter
  bf16x8 wxf[4][8], whf[4][8];
#pragma unroll
  for (int ct = 0; ct < 4; ++ct) {
#pragma unroll
    for (int ks = 0; ks < 8; ++ks) {
      bf16x8 vx, vh;
#pragma unroll
      for (int e = 0; e < 8; ++e) {
        const size_t k = (size_t)(kb + ks * 32 + krow + e);
        vx[e] = (short)f2bf(Wx[k * kG + ct * kH + colc]);
        vh[e] = (short)f2bf(Wh[k * kG + ct * kH + colc]);
      }
      wxf[ct][ks] = vx;
      whf[ct][ks] = vh;
    }
  }

  // gate-phase identity
  const int n_l = tid >> 4;
  const int j_l = tid & 15;
  const int jg = ug * 16 + j_l;
  const float b_i = bias[jg];
  const float b_f = bias[kH + jg];
  const float b_o = bias[2 * kH + jg];
  const float b_g = bias[3 * kH + jg];
  float c = 0.0f;

  // A-fragment identity
  const int arow = lane & 15;
  const int nrow = dom * 16 + arow;
  const unsigned long long xbase0 =
      (unsigned long long)nrow * kT * kD * 2 + (unsigned long long)(kb + krow) * 2;
  const unsigned long long hbase0 =
      (unsigned long long)nrow * kH * 2 + (unsigned long long)(kb + krow) * 2;

  // barrier plumbing: 64 counter lines/domain + 1 epoch-flag line/domain
  unsigned int* mycnt = cnt + (size_t)(dom * 64 + ug) * 32;  // this WG's line
  unsigned int* dcnt = cnt + (size_t)dom * 64 * 32;          // domain counter base
  unsigned int* dflag = cnt + 8192 + (size_t)dom * 32;       // domain epoch flag
  const bool is_agg = (ug == 0) && (wv == 0);

  bf16x8 xfrag[8], hfrag[8];

  // ---- prologue: x(0) frags + h0 frags
  if (PRE) {
    const unsigned long long xb = (unsigned long long)xbf + xbase0;
#pragma unroll
    for (int ks = 0; ks < 8; ++ks) xfrag[ks] = gld16(xb + (unsigned)(ks * 64));
  } else {
    const float* xr = x + (size_t)nrow * kT * kD + (kb + krow);
#pragma unroll
    for (int ks = 0; ks < 8; ++ks) {
      const float4 f0 = *(const float4*)(xr + ks * 32);
      const float4 f1 = *(const float4*)(xr + ks * 32 + 4);
      bf16x8 v;
      v[0] = (short)f2bf(f0.x); v[1] = (short)f2bf(f0.y);
      v[2] = (short)f2bf(f0.z); v[3] = (short)f2bf(f0.w);
      v[4] = (short)f2bf(f1.x); v[5] = (short)f2bf(f1.y);
      v[6] = (short)f2bf(f1.z); v[7] = (short)f2bf(f1.w);
      xfrag[ks] = v;
    }
  }
  {
    const float* hr = h0 + (size_t)nrow * kH + (kb + krow);
#pragma unroll
    for (int ks = 0; ks < 8; ++ks) {
      const float4 f0 = *(const float4*)(hr + ks * 32);
      const float4 f1 = *(const float4*)(hr + ks * 32 + 4);
      bf16x8 v;
      v[0] = (short)f2bf(f0.x); v[1] = (short)f2bf(f0.y);
      v[2] = (short)f2bf(f0.z); v[3] = (short)f2bf(f0.w);
      v[4] = (short)f2bf(f1.x); v[5] = (short)f2bf(f1.y);
      v[6] = (short)f2bf(f1.z); v[7] = (short)f2bf(f1.w);
      hfrag[ks] = v;
    }
  }
  asm volatile("s_waitcnt vmcnt(0)" ::: "memory");  // asm loads opaque to compiler
  __builtin_amdgcn_sched_barrier(0);

  // acc starts with the x-half of step 0
  f32x4 acc[4];
#pragma unroll
  for (int ct = 0; ct < 4; ++ct) acc[ct] = (f32x4){0.f, 0.f, 0.f, 0.f};
#pragma unroll
  for (int ks = 0; ks < 8; ++ks)
#pragma unroll
    for (int ct = 0; ct < 4; ++ct)
      acc[ct] = __builtin_amdgcn_mfma_f32_16x16x32_bf16(xfrag[ks], wxf[ct][ks], acc[ct], 0, 0, 0);

  for (int t = 0; t < kT; ++t) {
    // ---- h-half MFMAs (split wait on the 8 in-flight hfrag loads)
    asm volatile("s_waitcnt vmcnt(4)" ::: "memory");
    __builtin_amdgcn_sched_barrier(0);
#pragma unroll
    for (int ks = 0; ks < 4; ++ks)
#pragma unroll
      for (int ct = 0; ct < 4; ++ct)
        acc[ct] = __builtin_amdgcn_mfma_f32_16x16x32_bf16(hfrag[ks], whf[ct][ks], acc[ct], 0, 0, 0);
    asm volatile("s_waitcnt vmcnt(0)" ::: "memory");
    __builtin_amdgcn_sched_barrier(0);
#pragma unroll
    for (int ks = 4; ks < 8; ++ks)
#pragma unroll
      for (int ct = 0; ct < 4; ++ct)
        acc[ct] = __builtin_amdgcn_mfma_f32_16x16x32_bf16(hfrag[ks], whf[ct][ks], acc[ct], 0, 0, 0);

    // ---- cross-wave K reduction: one ds_write_b128 per tile per lane
    // layout: ps[tile][col][row], col pitch 20 floats (80B, 16B-aligned slots)
#pragma unroll
    for (int ct = 0; ct < 4; ++ct) {
      const int o = (ct * 4 + wv) * 320 + (lane & 15) * 20 + (lane >> 4) * 4;
      *(f32x4*)&ps[o] = acc[ct];  // rows (l>>4)*4..+3 of col (l&15)
    }
    __syncthreads();

    float a4[4];
#pragma unroll
    for (int g = 0; g < 4; ++g) {
      a4[g] = ps[(g * 4 + 0) * 320 + j_l * 20 + n_l]
            + ps[(g * 4 + 1) * 320 + j_l * 20 + n_l]
            + ps[(g * 4 + 2) * 320 + j_l * 20 + n_l]
            + ps[(g * 4 + 3) * 320 + j_l * 20 + n_l];
    }
    const float gi = fsigmoid(a4[0] + b_i);
    const float gf = fsigmoid(a4[1] + b_f);
    const float go = fsigmoid(a4[2] + b_o);
    const float gg = ftanh(a4[3] + b_g);
    c = gf * c + gi * gg;
    const float hv = go * ftanh(c);

    if (t < kT - 1) {
      // ---- publish h(t+1): paired dword agent-scope store
      const unsigned mybf = (unsigned)f2bf(hv);
      const unsigned up = (unsigned)__shfl_xor((int)mybf, 1);
      if ((j_l & 1) == 0) {
        const size_t eidx = (size_t)((t + 1) & 1) * (kN * kH) +
                            (size_t)(dom * 16 + n_l) * kH + (size_t)(ug * 16 + j_l);
        __hip_atomic_store((unsigned*)(hbuf + eidx), mybf | (up << 16),
                           __ATOMIC_RELAXED, __HIP_MEMORY_SCOPE_AGENT);
      }
      // per-wave drain: THIS wave's publish stores acked at coherence point
      asm volatile("s_waitcnt vmcnt(0)" ::: "memory");
      __builtin_amdgcn_sched_barrier(0);
      if (lane == 0)
        __hip_atomic_fetch_add(mycnt, 1u, __ATOMIC_RELAXED, __HIP_MEMORY_SCOPE_AGENT);

      // out store AFTER arrival: its HBM ack is off the critical path
      __builtin_nontemporal_store(hv, &out[((size_t)(dom * 16 + n_l) * kT + t) * kH + jg]);

      // ---- x(t+1) frags + x-half MFMAs (hidden under the barrier wait)
      if (PRE) {
        const unsigned long long xb = (unsigned long long)xbf + xbase0 +
                                      (unsigned long long)(t + 1) * 2048u;
#pragma unroll
        for (int ks = 0; ks < 8; ++ks) xfrag[ks] = gld16(xb + (unsigned)(ks * 64));
        asm volatile("s_waitcnt vmcnt(0)" ::: "memory");  // also drains out-store
        __builtin_amdgcn_sched_barrier(0);
      } else {
        const float* xr = x + (size_t)nrow * kT * kD + (size_t)(t + 1) * kD + (kb + krow);
#pragma unroll
        for (int ks = 0; ks < 8; ++ks) {
          const float4 f0 = *(const float4*)(xr + ks * 32);
          const float4 f1 = *(const float4*)(xr + ks * 32 + 4);
          bf16x8 v;
          v[0] = (short)f2bf(f0.x); v[1] = (short)f2bf(f0.y);
          v[2] = (short)f2bf(f0.z); v[3] = (short)f2bf(f0.w);
          v[4] = (short)f2bf(f1.x); v[5] = (short)f2bf(f1.y);
          v[6] = (short)f2bf(f1.z); v[7] = (short)f2bf(f1.w);
          xfrag[ks] = v;
        }
      }
#pragma unroll
      for (int ct = 0; ct < 4; ++ct) acc[ct] = (f32x4){0.f, 0.f, 0.f, 0.f};
#pragma unroll
      for (int ks = 0; ks < 8; ++ks)
#pragma unroll
        for (int ct = 0; ct < 4; ++ct)
          acc[ct] = __builtin_amdgcn_mfma_f32_16x16x32_bf16(xfrag[ks], wxf[ct][ks], acc[ct], 0, 0, 0);

      // ---- barrier: aggregator gathers, others poll the epoch flag
      const unsigned tgt = (unsigned)(t + 1);
      if (is_agg) {
        for (;;) {
          unsigned v = __hip_atomic_load(dcnt + lane * 32, __ATOMIC_RELAXED,
                                         __HIP_MEMORY_SCOPE_AGENT);
#pragma unroll
          for (int s = 1; s < 64; s <<= 1) v += (unsigned)__shfl_xor((int)v, s);
          if (v >= 256u * tgt) break;  // 64 WGs x 4 waves per step
          __builtin_amdgcn_s_sleep(1);
        }
        if (lane == 0)
          __hip_atomic_store(dflag, tgt, __ATOMIC_RELAXED, __HIP_MEMORY_SCOPE_AGENT);
      } else if (lane == 0) {
        while (__hip_atomic_load(dflag, __ATOMIC_RELAXED, __HIP_MEMORY_SCOPE_AGENT) < tgt)
          __builtin_amdgcn_s_sleep(1);
      }
      asm volatile("" ::: "memory");
      __builtin_amdgcn_sched_barrier(0);

      // ---- issue h(t+1) frag loads (coherent), consumed at next iter top
      const unsigned long long hb = (unsigned long long)hbuf +
                                    (unsigned long long)((t + 1) & 1) * (kN * kH * 2) +
                                    hbase0;
#pragma unroll
      for (int ks = 0; ks < 8; ++ks) hfrag[ks] = gld16_coh(hb + (unsigned)(ks * 64));
    } else {
      __builtin_nontemporal_store(hv, &out[((size_t)(dom * 16 + n_l) * kT + t) * kH + jg]);
    }
  }
}

extern "C" void kernel_launch(void* const* d_in, const int* in_sizes, int n_in,
                              void* d_out, int out_size, void* d_ws, size_t ws_size,
                              hipStream_t stream) {
  (void)in_sizes; (void)n_in; (void)out_size;
  const float* x  = (const float*)d_in[0];
  const float* h0 = (const float*)d_in[1];
  const float* Wx = (const float*)d_in[2];
  const float* Wh = (const float*)d_in[3];
  const float* b  = (const float*)d_in[4];
  float* out = (float*)d_out;

  // ws: [0,32KB) 256 counter lines | [32KB,+512B) 4 flag lines | [36KB,+256KB)
  // h double buffer | [36KB+256KB, +64MB) bf16 x
  unsigned int* cnt = (unsigned int*)d_ws;
  unsigned short* hbuf = (unsigned short*)((char*)d_ws + 36864);
  unsigned short* xbf = (unsigned short*)((char*)d_ws + 36864 + (size_t)2 * kN * kH * 2);
  const size_t need_pre = 36864 + (size_t)2 * kN * kH * 2 + (size_t)kN * kT * kD * 2;

  hipMemsetAsync(d_ws, 0, 36864, stream);  // reset counters+flags (capture-legal)

  if (ws_size >= need_pre) {
    hipLaunchKernelGGL(xconv, dim3(2048), dim3(256), 0, stream, x, xbf);
    hipLaunchKernelGGL(HIP_KERNEL_NAME(lstm_persistent<true>), dim3(256), dim3(256),
                       0, stream, x, h0, Wx, Wh, b, out, hbuf, cnt, xbf);
  } else {
    hipLaunchKernelGGL(HIP_KERNEL_NAME(lstm_persistent<false>), dim3(256), dim3(256),
                       0, stream, x, h0, Wx, Wh, b, out, hbuf, cnt,
                       (const unsigned short*)nullptr);
  }
}